// Round 1
// baseline (441.949 us; speedup 1.0000x reference)
//
#include <hip/hip_runtime.h>

typedef _Float16 half8 __attribute__((ext_vector_type(8)));
typedef float    floatx4 __attribute__((ext_vector_type(4)));

// ws layout: [0, 25165824) embeds f16 [16384][6][128]; then Wt f16 (589824 elems)
#define EMB_BYTES 25165824u

// ---------------------------------------------------------------------------
// prep: Wp_i [d][128] f32  ->  Wt_i [128][dpad] f16 (transposed, zero-padded)
// ---------------------------------------------------------------------------
extern "C" __global__ __launch_bounds__(256) void k_prep(
    const float* __restrict__ Wp0, const float* __restrict__ Wp1,
    const float* __restrict__ Wp2, const float* __restrict__ Wp3,
    const float* __restrict__ Wp4, const float* __restrict__ Wp5,
    _Float16* __restrict__ Wt)
{
  const int DPAD_[6] = {2048,192,768,512,768,320};
  int j = blockIdx.x*256 + threadIdx.x;   // 73728 jobs total (= 16*sum(dpad))
  int i = 0, st = 0, cum = 0;
  #pragma unroll
  for (int q = 0; q < 6; q++){
    int sz = DPAD_[q] << 4;               // jobs per branch = 128 * dpad/8
    if (j >= cum){ i = q; st = cum; }
    cum += sz;
  }
  int local = j - st;
  int kc = local >> 7;                    // k-chunk of 8
  int c  = local & 127;                   // output column (0..127)
  const float* Wp; int d, dpad, woff;
  switch(i){
    case 0:  Wp=Wp0; d=2048; dpad=2048; woff=0;      break;
    case 1:  Wp=Wp1; d=167;  dpad=192;  woff=262144; break;
    case 2:  Wp=Wp2; d=768;  dpad=768;  woff=286720; break;
    case 3:  Wp=Wp3; d=512;  dpad=512;  woff=385024; break;
    case 4:  Wp=Wp4; d=768;  dpad=768;  woff=450560; break;
    default: Wp=Wp5; d=300;  dpad=320;  woff=548864; break;
  }
  half8 h;
  #pragma unroll
  for (int u = 0; u < 8; u++){
    int k = (kc<<3) + u;
    float v = (k < d) ? Wp[(size_t)k*128 + c] : 0.0f;
    h[u] = (_Float16)v;
  }
  *(half8*)(Wt + woff + (size_t)c*dpad + (kc<<3)) = h;
}

// ---------------------------------------------------------------------------
// projection GEMM: embeds[row][i][col] = x_i[row][:] @ Wp_i + bp_i   (f16 out)
// 128x128 tile, 4 waves (2x2), f16 MFMA 16x16x32, A via LDS, B direct from L2
// ---------------------------------------------------------------------------
__device__ __forceinline__ void load_a16(const float* __restrict__ xrow,
                                         int kb, int d, bool vec4, float* a)
{
  if (vec4 && (kb + 16 <= d)){
    const float4* p = reinterpret_cast<const float4*>(xrow + kb);
    float4 v0 = p[0], v1 = p[1], v2 = p[2], v3 = p[3];
    a[0]=v0.x;  a[1]=v0.y;  a[2]=v0.z;  a[3]=v0.w;
    a[4]=v1.x;  a[5]=v1.y;  a[6]=v1.z;  a[7]=v1.w;
    a[8]=v2.x;  a[9]=v2.y;  a[10]=v2.z; a[11]=v2.w;
    a[12]=v3.x; a[13]=v3.y; a[14]=v3.z; a[15]=v3.w;
  } else {
    #pragma unroll
    for (int u = 0; u < 16; u++){
      int k = kb + u;
      a[u] = (k < d) ? xrow[k] : 0.0f;
    }
  }
}

__device__ __forceinline__ void cvt_store_a(const float* a, _Float16* dst)
{
  half8 h0, h1;
  #pragma unroll
  for (int u = 0; u < 8; u++){ h0[u] = (_Float16)a[u]; h1[u] = (_Float16)a[8+u]; }
  *(half8*)(dst)     = h0;
  *(half8*)(dst + 8) = h1;
}

extern "C" __global__ __launch_bounds__(256) void k_proj(
    const float* __restrict__ x0, const float* __restrict__ x1,
    const float* __restrict__ x2, const float* __restrict__ x3,
    const float* __restrict__ x4, const float* __restrict__ x5,
    const float* __restrict__ bp0, const float* __restrict__ bp1,
    const float* __restrict__ bp2, const float* __restrict__ bp3,
    const float* __restrict__ bp4, const float* __restrict__ bp5,
    const _Float16* __restrict__ Wt, _Float16* __restrict__ Eo)
{
  __shared__ _Float16 sA[2][128][40];   // 40 = 32 + 8 pad (bank-friendly)

  int bl = blockIdx.x;
  int slot = bl % 6;          // interleave branches so heavy blocks spread
  int mtile = bl / 6;
  const float* x; const float* bp; int i, d, dpad, woff;
  switch(slot){
    case 0:  i=0; x=x0; bp=bp0; d=2048; dpad=2048; woff=0;      break;
    case 1:  i=2; x=x2; bp=bp2; d=768;  dpad=768;  woff=286720; break;
    case 2:  i=4; x=x4; bp=bp4; d=768;  dpad=768;  woff=450560; break;
    case 3:  i=3; x=x3; bp=bp3; d=512;  dpad=512;  woff=385024; break;
    case 4:  i=5; x=x5; bp=bp5; d=300;  dpad=320;  woff=548864; break;
    default: i=1; x=x1; bp=bp1; d=167;  dpad=192;  woff=262144; break;
  }
  int NT = dpad >> 5;
  bool vec4 = ((d & 3) == 0);
  const _Float16* wt = Wt + woff;
  int row0 = mtile << 7;

  int t = threadIdx.x;
  int lane = t & 63, wid = t >> 6;
  int wr = wid >> 1, wc = wid & 1;
  int l15 = lane & 15, l4 = lane >> 4;
  int srow = t >> 1, shalf = t & 1;
  const float* xrow = x + (size_t)(row0 + srow)*d;

  const _Float16* bbase[4];
  #pragma unroll
  for (int nt = 0; nt < 4; nt++)
    bbase[nt] = wt + (size_t)((wc<<6) + (nt<<4) + l15)*dpad + (l4<<3);

  floatx4 acc[4][4];
  #pragma unroll
  for (int a_ = 0; a_ < 4; a_++)
    #pragma unroll
    for (int b_ = 0; b_ < 4; b_++)
      #pragma unroll
      for (int q = 0; q < 4; q++) acc[a_][b_][q] = 0.0f;

  // prologue: stage kt=0
  {
    float a0[16];
    load_a16(xrow, (shalf<<4), d, vec4, a0);
    cvt_store_a(a0, &sA[0][srow][shalf<<4]);
  }
  half8 bcur[4];
  #pragma unroll
  for (int nt = 0; nt < 4; nt++) bcur[nt] = *(const half8*)(bbase[nt]);
  __syncthreads();

  for (int kt = 0; kt < NT; kt++){
    int cur = kt & 1;
    bool more = (kt + 1) < NT;
    float anx[16]; half8 bnxt[4];
    if (more){
      load_a16(xrow, ((kt+1)<<5) + (shalf<<4), d, vec4, anx);
      #pragma unroll
      for (int nt = 0; nt < 4; nt++)
        bnxt[nt] = *(const half8*)(bbase[nt] + ((kt+1)<<5));
    }
    #pragma unroll
    for (int mtl = 0; mtl < 4; mtl++){
      half8 af = *(const half8*)&sA[cur][(wr<<6)+(mtl<<4)+l15][l4<<3];
      #pragma unroll
      for (int nt = 0; nt < 4; nt++)
        acc[mtl][nt] = __builtin_amdgcn_mfma_f32_16x16x32_f16(af, bcur[nt], acc[mtl][nt], 0, 0, 0);
    }
    if (more){
      cvt_store_a(anx, &sA[cur^1][srow][shalf<<4]);
      #pragma unroll
      for (int nt = 0; nt < 4; nt++) bcur[nt] = bnxt[nt];
    }
    __syncthreads();
  }

  // epilogue: bias + f16 store. C layout: col=lane&15, row=(lane>>4)*4+j
  #pragma unroll
  for (int nt = 0; nt < 4; nt++){
    int col = (wc<<6) + (nt<<4) + l15;
    float bv = bp[col];
    #pragma unroll
    for (int mtl = 0; mtl < 4; mtl++){
      int rbase = row0 + (wr<<6) + (mtl<<4) + (l4<<2);
      #pragma unroll
      for (int j = 0; j < 4; j++){
        float v = acc[mtl][nt][j] + bv;
        Eo[(size_t)(rbase + j)*768 + i*128 + col] = (_Float16)v;
      }
    }
  }
}

// ---------------------------------------------------------------------------
// attention/fusion: per 32 rows -> MLP scores (f16 MFMA), cosine comp,
// task gate, masked softmax, weighted fusion. f32 output.
// ---------------------------------------------------------------------------
extern "C" __global__ __launch_bounds__(256) void k_attn(
    const _Float16* __restrict__ E,
    const float* __restrict__ W1, const float* __restrict__ b1,
    const float* __restrict__ W2, const float* __restrict__ b2,
    const float* __restrict__ beta_,
    const float* __restrict__ Wg, const float* __restrict__ bg,
    const float* __restrict__ ctx, float* __restrict__ out)
{
  __shared__ _Float16 eb[192][136];   // 32 rows * 6 branches, k padded 128->136
  __shared__ _Float16 w1t[64][136];   // W1 transposed [h][k]
  __shared__ float s_s1[192];
  __shared__ float s_gate[192];

  int t = threadIdx.x;
  int row0 = blockIdx.x << 5;
  int lane = t & 63, wid = t >> 6;
  int l15 = lane & 15, l4 = lane >> 4;

  // ---- phase 1: stage embeds + W1, compute task gate ----
  {
    const _Float16* src = E + (size_t)row0*768;
    #pragma unroll
    for (int jj = 0; jj < 12; jj++){
      int off8 = t + (jj<<8);           // < 3072 (192*128/8)
      half8 v = *(const half8*)(src + ((size_t)off8<<3));
      int mrow = off8 >> 4; int kq = off8 & 15;
      *(half8*)&eb[mrow][kq<<3] = v;
    }
    #pragma unroll
    for (int jj = 0; jj < 8; jj++){
      int idx4 = t + (jj<<8);           // < 2048 (128*64/4)
      float4 v = *(const float4*)(W1 + ((size_t)idx4<<2));
      int k = idx4 >> 4; int h4 = (idx4 & 15) << 2;
      w1t[h4  ][k] = (_Float16)v.x;
      w1t[h4+1][k] = (_Float16)v.y;
      w1t[h4+2][k] = (_Float16)v.z;
      w1t[h4+3][k] = (_Float16)v.w;
    }
    if (t < 192){
      int r = t / 6; int n = t - r*6;
      const float* cr = ctx + (size_t)(row0 + r)*16;
      float g = bg[n];
      #pragma unroll
      for (int k = 0; k < 16; k++) g += cr[k] * Wg[k*6 + n];
      s_gate[t] = g;
    }
  }
  __syncthreads();

  // ---- phase 2: s1 = relu(E@W1 + b1) @ W2 + b2, via f16 MFMA ----
  {
    floatx4 acc[3][4];
    #pragma unroll
    for (int a_ = 0; a_ < 3; a_++)
      #pragma unroll
      for (int b_ = 0; b_ < 4; b_++)
        #pragma unroll
        for (int q = 0; q < 4; q++) acc[a_][b_][q] = 0.0f;

    #pragma unroll
    for (int ks = 0; ks < 4; ks++){
      half8 bf[4];
      #pragma unroll
      for (int nt = 0; nt < 4; nt++)
        bf[nt] = *(const half8*)&w1t[(nt<<4)+l15][(ks<<5)+(l4<<3)];
      #pragma unroll
      for (int m3 = 0; m3 < 3; m3++){
        half8 af = *(const half8*)&eb[wid*48 + (m3<<4) + l15][(ks<<5)+(l4<<3)];
        #pragma unroll
        for (int nt = 0; nt < 4; nt++)
          acc[m3][nt] = __builtin_amdgcn_mfma_f32_16x16x32_f16(af, bf[nt], acc[m3][nt], 0, 0, 0);
      }
    }
    float vb1[4], vw2[4];
    #pragma unroll
    for (int nt = 0; nt < 4; nt++){
      int col = (nt<<4) + l15;
      vb1[nt] = b1[col]; vw2[nt] = W2[col];
    }
    float b2v = b2[0];
    #pragma unroll
    for (int m3 = 0; m3 < 3; m3++){
      #pragma unroll
      for (int j = 0; j < 4; j++){
        float p = 0.0f;
        #pragma unroll
        for (int nt = 0; nt < 4; nt++){
          float v = acc[m3][nt][j] + vb1[nt];
          v = fmaxf(v, 0.0f);
          p += v * vw2[nt];
        }
        p += __shfl_xor(p, 1); p += __shfl_xor(p, 2);
        p += __shfl_xor(p, 4); p += __shfl_xor(p, 8);
        if (l15 == 0) s_s1[wid*48 + (m3<<4) + (l4<<2) + j] = p + b2v;
      }
    }
  }
  __syncthreads();

  // ---- phase 3: per-row norms/cos/softmax/fusion (wave per 8 rows) ----
  {
    float BETA = beta_[0];
    for (int rr = 0; rr < 8; rr++){
      int lrow = (wid<<3) + rr;
      float e0[6], e1[6];
      #pragma unroll
      for (int n = 0; n < 6; n++){
        e0[n] = (float)eb[lrow*6+n][lane];
        e1[n] = (float)eb[lrow*6+n][64+lane];
      }
      float red[21];
      int c = 0;
      #pragma unroll
      for (int n = 0; n < 6; n++) red[c++] = e0[n]*e0[n] + e1[n]*e1[n];
      #pragma unroll
      for (int n = 0; n < 6; n++){
        #pragma unroll
        for (int m = n+1; m < 6; m++) red[c++] = e0[n]*e0[m] + e1[n]*e1[m];
      }
      #pragma unroll
      for (int q = 0; q < 21; q++){
        float v = red[q];
        v += __shfl_xor(v, 1);  v += __shfl_xor(v, 2);  v += __shfl_xor(v, 4);
        v += __shfl_xor(v, 8);  v += __shfl_xor(v, 16); v += __shfl_xor(v, 32);
        red[q] = v;
      }
      float den[6]; bool val[6];
      #pragma unroll
      for (int n = 0; n < 6; n++){
        val[n] = red[n] > 1e-16f;                 // norm > 1e-8
        den[n] = fmaxf(sqrtf(red[n]), 1e-12f);
      }
      float csum[6];
      #pragma unroll
      for (int n = 0; n < 6; n++) csum[n] = red[n] / (den[n]*den[n]);
      {
        int cc = 6;
        #pragma unroll
        for (int n = 0; n < 6; n++){
          #pragma unroll
          for (int m = n+1; m < 6; m++){
            float cv = red[cc++] / (den[n]*den[m]);
            csum[n] += cv; csum[m] += cv;
          }
        }
      }
      float sc[6];
      #pragma unroll
      for (int n = 0; n < 6; n++){
        float comp = 1.0f - csum[n]*(1.0f/6.0f);
        float s = s_s1[lrow*6+n] + BETA*comp + s_gate[lrow*6+n];
        sc[n] = val[n] ? s : -1e9f;
      }
      float mx = sc[0];
      #pragma unroll
      for (int n = 1; n < 6; n++) mx = fmaxf(mx, sc[n]);
      float wsum = 0.0f; float w[6];
      #pragma unroll
      for (int n = 0; n < 6; n++){ w[n] = __expf(sc[n]-mx); wsum += w[n]; }
      float inv = 1.0f / wsum;
      float f0 = 0.0f, f1 = 0.0f;
      #pragma unroll
      for (int n = 0; n < 6; n++){
        float wn = w[n]*inv;
        f0 += wn*e0[n]; f1 += wn*e1[n];
      }
      size_t ob = (size_t)(row0 + lrow)*128;
      out[ob + lane]      = f0;
      out[ob + 64 + lane] = f1;
    }
  }
}

// ---------------------------------------------------------------------------
extern "C" void kernel_launch(void* const* d_in, const int* in_sizes, int n_in,
                              void* d_out, int out_size, void* d_ws, size_t ws_size,
                              hipStream_t stream)
{
  const float* x0 = (const float*)d_in[0];
  const float* x1 = (const float*)d_in[1];
  const float* x2 = (const float*)d_in[2];
  const float* x3 = (const float*)d_in[3];
  const float* x4 = (const float*)d_in[4];
  const float* x5 = (const float*)d_in[5];
  const float* ctx = (const float*)d_in[6];
  const float* Wp0 = (const float*)d_in[7];  const float* bp0 = (const float*)d_in[8];
  const float* Wp1 = (const float*)d_in[9];  const float* bp1 = (const float*)d_in[10];
  const float* Wp2 = (const float*)d_in[11]; const float* bp2 = (const float*)d_in[12];
  const float* Wp3 = (const float*)d_in[13]; const float* bp3 = (const float*)d_in[14];
  const float* Wp4 = (const float*)d_in[15]; const float* bp4 = (const float*)d_in[16];
  const float* Wp5 = (const float*)d_in[17]; const float* bp5 = (const float*)d_in[18];
  const float* W1 = (const float*)d_in[19];
  const float* b1 = (const float*)d_in[20];
  const float* W2 = (const float*)d_in[21];
  const float* b2 = (const float*)d_in[22];
  const float* beta = (const float*)d_in[23];
  const float* Wg = (const float*)d_in[24];
  const float* bg = (const float*)d_in[25];

  _Float16* ws_e = (_Float16*)d_ws;                              // embeds f16
  _Float16* Wt   = (_Float16*)((char*)d_ws + EMB_BYTES);         // weights f16
  float* outp = (float*)d_out;

  k_prep<<<288, 256, 0, stream>>>(Wp0, Wp1, Wp2, Wp3, Wp4, Wp5, Wt);
  k_proj<<<768, 256, 0, stream>>>(x0, x1, x2, x3, x4, x5,
                                  bp0, bp1, bp2, bp3, bp4, bp5, Wt, ws_e);
  k_attn<<<512, 256, 0, stream>>>(ws_e, W1, b1, W2, b2, beta, Wg, bg, ctx, outp);
}